// Round 3
// baseline (108.713 us; speedup 1.0000x reference)
//
#include <hip/hip_runtime.h>

// DA-RNN (LSTM_price): T=10, D=45, H=45. fp32 in/out/compute (round-1 NaN
// proved inputs are fp32; round-2 error signature proved output is fp32).
// Single workgroup, single launch: latency-bound serial chain of 10 LSTM
// steps + small decoder.
//
// Algebraic simplifications vs reference (verified):
//  - encoder input-attention softmax is shift-invariant => h/c/ba terms cancel;
//    attn over D is time-invariant, computed once. Wa[0:90], ba dead.
//  - encoder gate input-half Gx[t][g] precomputed in parallel for all t.
//  - decoder h0=c0=0 => Whh_d dead, b2 cancels in softmax, c2 = sig(i)*tanh(g).

static constexpr int NT = 10;     // time steps
static constexpr int ND = 45;     // input features
static constexpr int NH = 45;     // hidden
static constexpr int NG = 4 * NH; // 180 gates

__device__ __forceinline__ float sigf(float x) {
    return 1.0f / (1.0f + __expf(-x));
}

__global__ __launch_bounds__(256) void darnn_kernel(
    const float* __restrict__ X,      // [T,D] 450
    const float* __restrict__ Wa,     // [1,2H+T] 100 (only [90:100] live)
    const float* __restrict__ Wih_e,  // [4H,D]
    const float* __restrict__ Whh_e,  // [4H,H]
    const float* __restrict__ bih_e,  // 180
    const float* __restrict__ bhh_e,  // 180
    const float* __restrict__ W1,     // [D,2H+D] (cols 90:135 live)
    const float* __restrict__ b1,     // 45
    const float* __restrict__ W2,     // [1,D] 45
    const float* __restrict__ Wih_d,  // [4H,D]
    const float* __restrict__ bih_d,  // 180
    const float* __restrict__ bhh_d,  // 180
    const float* __restrict__ Wfc,    // [45,2H]
    const float* __restrict__ bfc,    // 45
    float* __restrict__ out)          // 45 fp32
{
    const int tid = threadIdx.x;

    __shared__ float sX[NT * ND];
    __shared__ float sWi[NT * ND];
    __shared__ float sWhh[NG * NH];   // 32.4 KB
    __shared__ float sGx[NT * NG];
    __shared__ float sh[NH], sc[NH];
    __shared__ float sgates[NG];
    __shared__ float shs[NT * NH];
    __shared__ float sattn[ND];
    __shared__ float sdec[NT * NH];
    __shared__ float sat[NT];
    __shared__ float sctx[NH];
    __shared__ float sh1[NH];

    // ---- stage input / recurrent weights into LDS ----
    for (int i = tid; i < NT * ND; i += 256) sX[i] = X[i];
    for (int i = tid; i < NG * NH; i += 256) sWhh[i] = Whh_e[i];
    if (tid < NH) { sh[tid] = 0.0f; sc[tid] = 0.0f; }
    __syncthreads();

    // ---- input attention (time-invariant): attn = softmax_d(sum_t Wa[90+t]*X[t,d]) ----
    if (tid < 64) {
        float acc = -1e30f;
        if (tid < ND) {
            acc = 0.0f;
            for (int t = 0; t < NT; ++t) acc += Wa[90 + t] * sX[t * ND + tid];
        }
        float m = acc;
        for (int off = 32; off; off >>= 1) m = fmaxf(m, __shfl_xor(m, off, 64));
        float e = (tid < ND) ? __expf(acc - m) : 0.0f;
        float s = e;
        for (int off = 32; off; off >>= 1) s += __shfl_xor(s, off, 64);
        if (tid < ND) sattn[tid] = e / s;
    }
    __syncthreads();

    for (int i = tid; i < NT * ND; i += 256) sWi[i] = sattn[i % ND] * sX[i];
    __syncthreads();

    // ---- precompute input-half of encoder gates for all t (parallel) ----
    for (int i = tid; i < NT * NG; i += 256) {
        const int t = i / NG, g = i % NG;
        const float* __restrict__ wr = Wih_e + g * ND;
        const float* wi = sWi + t * ND;
        float a0 = bih_e[g] + bhh_e[g], a1 = 0.f, a2 = 0.f, a3 = 0.f;
        int d = 0;
        for (; d + 3 < ND; d += 4) {
            a0 += wr[d]     * wi[d];
            a1 += wr[d + 1] * wi[d + 1];
            a2 += wr[d + 2] * wi[d + 2];
            a3 += wr[d + 3] * wi[d + 3];
        }
        for (; d < ND; ++d) a0 += wr[d] * wi[d];
        sGx[i] = (a0 + a1) + (a2 + a3);
    }
    __syncthreads();

    // ---- sequential encoder recurrence: 10 x (180x45 LDS matvec + activations) ----
    for (int t = 0; t < NT; ++t) {
        if (tid < NG) {
            const float* wr = sWhh + tid * NH;
            float a0 = sGx[t * NG + tid], a1 = 0.f, a2 = 0.f, a3 = 0.f;
            int k = 0;
            for (; k + 3 < NH; k += 4) {
                a0 += wr[k]     * sh[k];
                a1 += wr[k + 1] * sh[k + 1];
                a2 += wr[k + 2] * sh[k + 2];
                a3 += wr[k + 3] * sh[k + 3];
            }
            for (; k < NH; ++k) a0 += wr[k] * sh[k];
            sgates[tid] = (a0 + a1) + (a2 + a3);
        }
        __syncthreads();
        if (tid < NH) {
            float ig = sigf(sgates[tid]);
            float fg = sigf(sgates[NH + tid]);
            float gg = tanhf(sgates[2 * NH + tid]);
            float og = sigf(sgates[3 * NH + tid]);
            float c2 = fg * sc[tid] + ig * gg;
            float h2 = og * tanhf(c2);
            sc[tid] = c2;
            sh[tid] = h2;
            shs[t * NH + tid] = h2;
        }
        __syncthreads();
    }

    // ---- decoder temporal attention (h0=c0=0 => only price_vec cols of W1 live) ----
    for (int i = tid; i < NT * NH; i += 256) {
        const int t = i / NH, k = i % NH;
        const float* __restrict__ wr = W1 + k * (2 * NH + ND) + 2 * NH; // cols 90:135
        const float* hv = shs + t * NH;
        float a0 = b1[k], a1 = 0.f, a2 = 0.f, a3 = 0.f;
        int j = 0;
        for (; j + 3 < ND; j += 4) {
            a0 += wr[j]     * hv[j];
            a1 += wr[j + 1] * hv[j + 1];
            a2 += wr[j + 2] * hv[j + 2];
            a3 += wr[j + 3] * hv[j + 3];
        }
        for (; j < ND; ++j) a0 += wr[j] * hv[j];
        sdec[i] = W2[k] * tanhf((a0 + a1) + (a2 + a3));
    }
    __syncthreads();

    if (tid < NT) {
        float acc = 0.0f;
        for (int k = 0; k < NH; ++k) acc += sdec[tid * NH + k];
        sat[tid] = acc; // b2 cancels in softmax
    }
    __syncthreads();
    if (tid == 0) {
        float m = -1e30f;
        for (int t = 0; t < NT; ++t) m = fmaxf(m, sat[t]);
        float e[NT], s = 0.0f;
        for (int t = 0; t < NT; ++t) { e[t] = __expf(sat[t] - m); s += e[t]; }
        float inv = 1.0f / s;
        for (int t = 0; t < NT; ++t) sat[t] = e[t] * inv;
    }
    __syncthreads();

    if (tid < NH) {
        float acc = 0.0f;
        for (int t = 0; t < NT; ++t) acc += sat[t] * shs[t * NH + tid];
        sctx[tid] = acc;
    }
    __syncthreads();

    // ---- decoder LSTM step (h=c=0): gates = Wih_d @ ctx + bih_d + bhh_d ----
    if (tid < NG) {
        const float* __restrict__ wr = Wih_d + tid * ND;
        float a0 = bih_d[tid] + bhh_d[tid], a1 = 0.f, a2 = 0.f, a3 = 0.f;
        int d = 0;
        for (; d + 3 < ND; d += 4) {
            a0 += wr[d]     * sctx[d];
            a1 += wr[d + 1] * sctx[d + 1];
            a2 += wr[d + 2] * sctx[d + 2];
            a3 += wr[d + 3] * sctx[d + 3];
        }
        for (; d < ND; ++d) a0 += wr[d] * sctx[d];
        sgates[tid] = (a0 + a1) + (a2 + a3);
    }
    __syncthreads();
    if (tid < NH) {
        float ig = sigf(sgates[tid]);
        float gg = tanhf(sgates[2 * NH + tid]);
        float og = sigf(sgates[3 * NH + tid]);
        float c2 = ig * gg; // c0 = 0 => f-gate term drops
        sh1[tid] = og * tanhf(c2);
    }
    __syncthreads();

    // ---- final fc: y = [h1, ctx] @ Wfc.T + bfc ----
    if (tid < 45) {
        const float* __restrict__ wr = Wfc + tid * (2 * NH);
        float a0 = bfc[tid], a1 = 0.f;
        for (int j = 0; j < NH; ++j) {
            a0 += wr[j]      * sh1[j];
            a1 += wr[NH + j] * sctx[j];
        }
        out[tid] = a0 + a1;
    }
}

extern "C" void kernel_launch(void* const* d_in, const int* in_sizes, int n_in,
                              void* d_out, int out_size, void* d_ws, size_t ws_size,
                              hipStream_t stream) {
    const float* X     = (const float*)d_in[0];
    const float* Wa    = (const float*)d_in[1];
    // d_in[2] = ba — dead (cancels in feature softmax)
    const float* Wih_e = (const float*)d_in[3];
    const float* Whh_e = (const float*)d_in[4];
    const float* bih_e = (const float*)d_in[5];
    const float* bhh_e = (const float*)d_in[6];
    const float* W1    = (const float*)d_in[7];
    const float* b1    = (const float*)d_in[8];
    const float* W2    = (const float*)d_in[9];
    // d_in[10] = b2 — dead (cancels in temporal softmax)
    const float* Wih_d = (const float*)d_in[11];
    // d_in[12] = Whh_d — dead (decoder h0 = 0)
    const float* bih_d = (const float*)d_in[13];
    const float* bhh_d = (const float*)d_in[14];
    const float* Wfc   = (const float*)d_in[15];
    const float* bfc   = (const float*)d_in[16];
    float* out = (float*)d_out;

    darnn_kernel<<<dim3(1), dim3(256), 0, stream>>>(
        X, Wa, Wih_e, Whh_e, bih_e, bhh_e, W1, b1, W2,
        Wih_d, bih_d, bhh_d, Wfc, bfc, out);
}

// Round 5
// 104.723 us; speedup vs baseline: 1.0381x; 1.0381x over previous
//
#include <hip/hip_runtime.h>

// DA-RNN (LSTM_price): T=10, D=45, H=45. fp32 in/out/compute.
// Single workgroup, single launch, latency-optimized:
//  - wave 0 holds Whh_e in 180 VGPRs; the 10-step recurrence is pure
//    VALU + v_readlane (__shfl) — no LDS, no barriers inside the loop.
//  - waves 1-3 concurrently stage decoder weights: W1 live-cols + Wfc
//    into LDS, and each of 180 threads holds its own Wih_d row in
//    REGISTERS (45 VGPRs) — keeps static LDS at 40.5 KB (round-4 failed
//    at 73.7 KB > 64 KB static __shared__ limit).
// Algebra (verified, round-3 passed): Wa[0:90]/ba/b2/Whh_d dead;
// input attention time-invariant; decoder c2 = sig(i)*tanh(g).

static constexpr int NT = 10;
static constexpr int ND = 45;
static constexpr int NH = 45;
static constexpr int NG = 4 * NH; // 180

__device__ __forceinline__ float rcp_(float x) { return __builtin_amdgcn_rcpf(x); }
__device__ __forceinline__ float sigf(float x) { return rcp_(1.0f + __expf(-x)); }
__device__ __forceinline__ float tanh_(float x) { return 1.0f - 2.0f * rcp_(1.0f + __expf(2.0f * x)); }

__global__ __launch_bounds__(256) void darnn_kernel(
    const float* __restrict__ X,      // [T,D]
    const float* __restrict__ Wa,     // [1,2H+T] (only [90:100] live)
    const float* __restrict__ Wih_e,  // [4H,D]
    const float* __restrict__ Whh_e,  // [4H,H]
    const float* __restrict__ bih_e,  // [4H]
    const float* __restrict__ bhh_e,  // [4H]
    const float* __restrict__ W1,     // [D,2H+D] (cols 90:135 live)
    const float* __restrict__ b1,     // [D]
    const float* __restrict__ W2,     // [1,D]
    const float* __restrict__ Wih_d,  // [4H,D]
    const float* __restrict__ bih_d,  // [4H]
    const float* __restrict__ bhh_d,  // [4H]
    const float* __restrict__ Wfc,    // [45,2H]
    const float* __restrict__ bfc,    // [45]
    float* __restrict__ out)          // [45]
{
    const int tid  = threadIdx.x;
    const int wave = tid >> 6;
    const int lane = tid & 63;

    // static LDS total: 10,135 floats = 40,540 B  (< 65,536 B limit)
    __shared__ float sX[NT * ND];       //  450
    __shared__ float sattn[ND];         //   45
    __shared__ float sWi[NT * ND];      //  450
    __shared__ float sGx[NT * NG];      // 1800
    __shared__ float shs[NT * NH];      //  450
    __shared__ float sW1c[ND * ND];     // 2025 (live cols of W1)
    __shared__ float sWfc[45 * 2 * NH]; // 4050
    __shared__ float sb1[ND];           //   45
    __shared__ float sW2v[ND];          //   45
    __shared__ float sbfcv[45];         //   45
    __shared__ float sat[NT];           //   10
    __shared__ float sctx[NH];          //   45
    __shared__ float sh1v[NH];          //   45
    __shared__ float sg[NG];            //  180
    __shared__ float sdec[NT * NH];     //  450

    // ---- phase 0: wave 0 gathers Whh_e rows into registers;
    //      waves 1-3 stage X into LDS. These overlap. ----
    float w0[45], w1[45], w2[45], w3[45];
    if (wave == 0) {
        const int j = (lane < 45) ? lane : 0; // lanes 45-63 duplicate row 0 (harmless)
        const float* r0 = Whh_e + (j)       * NH;
        const float* r1 = Whh_e + (45 + j)  * NH;
        const float* r2 = Whh_e + (90 + j)  * NH;
        const float* r3 = Whh_e + (135 + j) * NH;
#pragma unroll
        for (int k = 0; k < 45; ++k) {
            w0[k] = r0[k]; w1[k] = r1[k]; w2[k] = r2[k]; w3[k] = r3[k];
        }
    } else {
        for (int i = tid - 64; i < NT * ND; i += 192) sX[i] = X[i];
    }
    __syncthreads();

    // ---- input attention (time-invariant), wave 1 only ----
    if (wave == 1) {
        const int l = lane;
        float acc = -1e30f;
        if (l < ND) {
            acc = 0.0f;
            for (int t = 0; t < NT; ++t) acc += Wa[90 + t] * sX[t * ND + l];
        }
        float m = acc;
        for (int off = 32; off; off >>= 1) m = fmaxf(m, __shfl_xor(m, off, 64));
        float e = (l < ND) ? __expf(acc - m) : 0.0f;
        float s = e;
        for (int off = 32; off; off >>= 1) s += __shfl_xor(s, off, 64);
        if (l < ND) sattn[l] = e * rcp_(s);
    }
    __syncthreads();

    if (wave > 0)
        for (int i = tid - 64; i < NT * ND; i += 192) sWi[i] = sattn[i % ND] * sX[i];
    __syncthreads();

    // ---- Gx[t][g]: input-half of encoder gates; each Wih_e element read ONCE ----
    if (wave > 0) {
        const int g = tid - 64;
        if (g < NG) {
            float acc[NT];
            const float b = bih_e[g] + bhh_e[g];
#pragma unroll
            for (int t = 0; t < NT; ++t) acc[t] = b;
            const float* wr = Wih_e + g * ND;
            for (int d = 0; d < ND; ++d) {
                const float wv = wr[d];
#pragma unroll
                for (int t = 0; t < NT; ++t) acc[t] += wv * sWi[t * ND + d];
            }
#pragma unroll
            for (int t = 0; t < NT; ++t) sGx[t * NG + g] = acc[t];
        }
    }
    __syncthreads();

    // ---- FORK: wave 0 runs the serial recurrence (register/VALU only);
    //      waves 1-3 stage decoder weights concurrently (Wih_d -> regs). ----
    float wd[45];          // per-thread Wih_d row (waves 1-3, g = tid-64 < 180)
    float bd = 0.0f;
    if (wave == 0) {
        const int j = (lane < 45) ? lane : 0;
        float h = 0.0f, c = 0.0f;
        for (int t = 0; t < NT; ++t) {
            float a0 = sGx[t * NG + j];
            float a1 = sGx[t * NG + 45 + j];
            float a2 = sGx[t * NG + 90 + j];
            float a3 = sGx[t * NG + 135 + j];
#pragma unroll
            for (int k = 0; k < 45; ++k) {
                const float hk = __shfl(h, k, 64);
                a0 += w0[k] * hk; a1 += w1[k] * hk;
                a2 += w2[k] * hk; a3 += w3[k] * hk;
            }
            c = sigf(a1) * c + sigf(a0) * tanh_(a2);
            h = sigf(a3) * tanh_(c);
            if (lane < 45) shs[t * NH + lane] = h;
        }
    } else {
        const int i0 = tid - 64; // 0..191
        if (i0 < NG) {           // Wih_d row -> registers
            const float* wr = Wih_d + i0 * ND;
#pragma unroll
            for (int d = 0; d < 45; ++d) wd[d] = wr[d];
            bd = bih_d[i0] + bhh_d[i0];
        }
        { // Wfc: 4050 floats = 2025 float2, coalesced
            const float2* s = (const float2*)Wfc;
            float2* d2 = (float2*)sWfc;
            for (int i = i0; i < 2025; i += 192) d2[i] = s[i];
        }
        // W1 live columns (90:135 of each 135-wide row)
        for (int i = i0; i < ND * ND; i += 192) {
            const int r = i / 45, cc = i - r * 45;
            sW1c[i] = W1[r * 135 + 90 + cc];
        }
        if (i0 < 45) { sb1[i0] = b1[i0]; sW2v[i0] = W2[i0]; sbfcv[i0] = bfc[i0]; }
    }
    __syncthreads();

    // ---- decoder temporal attention ----
    for (int i = tid; i < NT * NH; i += 256) {
        const int t = i / NH, k = i - t * NH;
        const float* wr = sW1c + k * ND;
        const float* hv = shs + t * NH;
        float a = sb1[k];
        for (int jj = 0; jj < ND; ++jj) a += wr[jj] * hv[jj];
        sdec[i] = sW2v[k] * tanh_(a);
    }
    __syncthreads();

    if (tid < NT) {
        float a = 0.0f;
        for (int k = 0; k < NH; ++k) a += sdec[tid * NH + k];
        sat[tid] = a; // b2 cancels in softmax
    }
    __syncthreads();
    if (tid == 0) {
        float m = -1e30f;
        for (int t = 0; t < NT; ++t) m = fmaxf(m, sat[t]);
        float e[NT], s = 0.0f;
        for (int t = 0; t < NT; ++t) { e[t] = __expf(sat[t] - m); s += e[t]; }
        const float inv = rcp_(s);
        for (int t = 0; t < NT; ++t) sat[t] = e[t] * inv;
    }
    __syncthreads();

    if (tid < NH) {
        float a = 0.0f;
        for (int t = 0; t < NT; ++t) a += sat[t] * shs[t * NH + tid];
        sctx[tid] = a;
    }
    __syncthreads();

    // ---- decoder LSTM (h=c=0): gate g computed by the thread holding row g ----
    if (wave > 0) {
        const int g = tid - 64;
        if (g < NG) {
            float a = bd;
#pragma unroll
            for (int d = 0; d < 45; ++d) a += wd[d] * sctx[d];
            sg[g] = a;
        }
    }
    __syncthreads();
    if (tid < NH) {
        const float ig = sigf(sg[tid]);
        const float gg = tanh_(sg[2 * NH + tid]);
        const float og = sigf(sg[3 * NH + tid]);
        sh1v[tid] = og * tanh_(ig * gg); // c0 = 0
    }
    __syncthreads();

    // ---- final fc: y = [h1, ctx] @ Wfc.T + bfc ----
    if (tid < 45) {
        const float* wr = sWfc + tid * (2 * NH);
        float a = sbfcv[tid];
        for (int jj = 0; jj < NH; ++jj) a += wr[jj] * sh1v[jj];
        for (int jj = 0; jj < NH; ++jj) a += wr[NH + jj] * sctx[jj];
        out[tid] = a;
    }
}

extern "C" void kernel_launch(void* const* d_in, const int* in_sizes, int n_in,
                              void* d_out, int out_size, void* d_ws, size_t ws_size,
                              hipStream_t stream) {
    const float* X     = (const float*)d_in[0];
    const float* Wa    = (const float*)d_in[1];
    // d_in[2] = ba — dead
    const float* Wih_e = (const float*)d_in[3];
    const float* Whh_e = (const float*)d_in[4];
    const float* bih_e = (const float*)d_in[5];
    const float* bhh_e = (const float*)d_in[6];
    const float* W1    = (const float*)d_in[7];
    const float* b1    = (const float*)d_in[8];
    const float* W2    = (const float*)d_in[9];
    // d_in[10] = b2 — dead
    const float* Wih_d = (const float*)d_in[11];
    // d_in[12] = Whh_d — dead
    const float* bih_d = (const float*)d_in[13];
    const float* bhh_d = (const float*)d_in[14];
    const float* Wfc   = (const float*)d_in[15];
    const float* bfc   = (const float*)d_in[16];
    float* out = (float*)d_out;

    darnn_kernel<<<dim3(1), dim3(256), 0, stream>>>(
        X, Wa, Wih_e, Whh_e, bih_e, bhh_e, W1, b1, W2,
        Wih_d, bih_d, bhh_d, Wfc, bfc, out);
}

// Round 6
// 103.429 us; speedup vs baseline: 1.0511x; 1.0125x over previous
//
#include <hip/hip_runtime.h>

// DA-RNN (LSTM_price): T=10, D=45, H=45. fp32 in/out/compute.
// Single workgroup (256 thr), single launch, latency-optimized:
//  - ALL cold global loads issued at t=0: wave 0 prefetches Whh_e into
//    180 VGPRs; each of 180 staging threads (waves 1-3) prefetches its
//    Wih_e row AND Wih_d row (+fused biases) into registers; waves 2-3
//    stage X into LDS concurrently. Fetch latency overlaps the
//    attention preamble instead of serializing after barriers.
//  - 10-step recurrence on wave 0: pure VALU + v_readlane (__shfl),
//    no LDS traffic, no barriers inside the loop.
//  - waves 1-3 stage Wfc / W1-live-cols during the chain (hidden).
// Algebra (verified, rounds 3/5 passed): Wa[0:90]/ba/b2/Whh_d dead;
// input attention time-invariant; decoder c2 = sig(i)*tanh(g).

static constexpr int NT = 10;
static constexpr int ND = 45;
static constexpr int NH = 45;
static constexpr int NG = 4 * NH; // 180

__device__ __forceinline__ float rcp_(float x) { return __builtin_amdgcn_rcpf(x); }
__device__ __forceinline__ float sigf(float x) { return rcp_(1.0f + __expf(-x)); }
__device__ __forceinline__ float tanh_(float x) { return 1.0f - 2.0f * rcp_(1.0f + __expf(2.0f * x)); }

__global__ __launch_bounds__(256) void darnn_kernel(
    const float* __restrict__ X,      // [T,D]
    const float* __restrict__ Wa,     // [1,2H+T] (only [90:100] live)
    const float* __restrict__ Wih_e,  // [4H,D]
    const float* __restrict__ Whh_e,  // [4H,H]
    const float* __restrict__ bih_e,  // [4H]
    const float* __restrict__ bhh_e,  // [4H]
    const float* __restrict__ W1,     // [D,2H+D] (cols 90:135 live)
    const float* __restrict__ b1,     // [D]
    const float* __restrict__ W2,     // [1,D]
    const float* __restrict__ Wih_d,  // [4H,D]
    const float* __restrict__ bih_d,  // [4H]
    const float* __restrict__ bhh_d,  // [4H]
    const float* __restrict__ Wfc,    // [45,2H]
    const float* __restrict__ bfc,    // [45]
    float* __restrict__ out)          // [45]
{
    const int tid  = threadIdx.x;
    const int wave = tid >> 6;
    const int lane = tid & 63;
    const int g    = tid - 64;        // staging-thread gate id (waves 1-3)

    // static LDS total: 10,135 floats = 40,540 B (< 64 KB static limit)
    __shared__ float sX[NT * ND];
    __shared__ float sattn[ND];
    __shared__ float sWi[NT * ND];
    __shared__ float sGx[NT * NG];
    __shared__ float shs[NT * NH];
    __shared__ float sW1c[ND * ND];
    __shared__ float sWfc[45 * 2 * NH];
    __shared__ float sb1[ND];
    __shared__ float sW2v[ND];
    __shared__ float sbfcv[45];
    __shared__ float sat[NT];
    __shared__ float sctx[NH];
    __shared__ float sh1v[NH];
    __shared__ float sg[NG];
    __shared__ float sdec[NT * NH];

    // ---- t=0: issue ALL cold fetches ----
    float w0[45], w1[45], w2[45], w3[45]; // wave 0: Whh_e
    float we[45], wd[45];                 // waves 1-3 (g<180): Wih_e / Wih_d rows
    float be = 0.0f, bd = 0.0f;
    if (wave == 0) {
        const int j = (lane < 45) ? lane : 0; // lanes 45-63 duplicate row 0
        const float* r0 = Whh_e + (j)       * NH;
        const float* r1 = Whh_e + (45 + j)  * NH;
        const float* r2 = Whh_e + (90 + j)  * NH;
        const float* r3 = Whh_e + (135 + j) * NH;
#pragma unroll
        for (int k = 0; k < 45; ++k) {
            w0[k] = r0[k]; w1[k] = r1[k]; w2[k] = r2[k]; w3[k] = r3[k];
        }
    } else {
        if (g < NG) {
            const float* wrE = Wih_e + g * ND;
            const float* wrD = Wih_d + g * ND;
#pragma unroll
            for (int d = 0; d < 45; ++d) { we[d] = wrE[d]; wd[d] = wrD[d]; }
            be = bih_e[g] + bhh_e[g];
            bd = bih_d[g] + bhh_d[g];
        }
        if (wave >= 2)
            for (int i = tid - 128; i < NT * ND; i += 128) sX[i] = X[i];
    }
    __syncthreads(); // B0: sX ready

    // ---- input attention (time-invariant) + sWi, wave 1 only ----
    if (wave == 1) {
        float acc = -1e30f;
        if (lane < ND) {
            acc = 0.0f;
            for (int t = 0; t < NT; ++t) acc += Wa[90 + t] * sX[t * ND + lane];
        }
        float m = acc;
        for (int off = 32; off; off >>= 1) m = fmaxf(m, __shfl_xor(m, off, 64));
        float e = (lane < ND) ? __expf(acc - m) : 0.0f;
        float s = e;
        for (int off = 32; off; off >>= 1) s += __shfl_xor(s, off, 64);
        if (lane < ND) sattn[lane] = e * rcp_(s);
        __builtin_amdgcn_s_waitcnt(0);      // sattn visible within the wave
        __builtin_amdgcn_wave_barrier();
        for (int i = lane; i < NT * ND; i += 64) sWi[i] = sattn[i % ND] * sX[i];
    }
    __syncthreads(); // B1: sWi ready

    // ---- Gx[t][g]: input-half of encoder gates (weights already in regs) ----
    if (wave > 0 && g < NG) {
        float acc[NT];
#pragma unroll
        for (int t = 0; t < NT; ++t) acc[t] = be;
        for (int d = 0; d < ND; ++d) {
            const float wv = we[d];
#pragma unroll
            for (int t = 0; t < NT; ++t) acc[t] += wv * sWi[t * ND + d];
        }
#pragma unroll
        for (int t = 0; t < NT; ++t) sGx[t * NG + g] = acc[t];
    }
    __syncthreads(); // B2: sGx ready

    // ---- FORK: wave 0 serial recurrence; waves 1-3 stage decoder LDS ----
    if (wave == 0) {
        const int j = (lane < 45) ? lane : 0;
        float h = 0.0f, c = 0.0f;
        for (int t = 0; t < NT; ++t) {
            float a0 = sGx[t * NG + j];
            float a1 = sGx[t * NG + 45 + j];
            float a2 = sGx[t * NG + 90 + j];
            float a3 = sGx[t * NG + 135 + j];
#pragma unroll
            for (int k = 0; k < 45; ++k) {
                const float hk = __shfl(h, k, 64);
                a0 += w0[k] * hk; a1 += w1[k] * hk;
                a2 += w2[k] * hk; a3 += w3[k] * hk;
            }
            c = sigf(a1) * c + sigf(a0) * tanh_(a2);
            h = sigf(a3) * tanh_(c);
            if (lane < 45) shs[t * NH + lane] = h;
        }
    } else {
        const int i0 = tid - 64; // 0..191
        { // Wfc: 4050 floats = 2025 float2, coalesced
            const float2* s2 = (const float2*)Wfc;
            float2* d2 = (float2*)sWfc;
            for (int i = i0; i < 2025; i += 192) d2[i] = s2[i];
        }
        // W1 live columns (90:135 of each 135-wide row)
        for (int i = i0; i < ND * ND; i += 192) {
            const int r = i / 45, cc = i - r * 45;
            sW1c[i] = W1[r * 135 + 90 + cc];
        }
        if (i0 < 45) { sb1[i0] = b1[i0]; sW2v[i0] = W2[i0]; sbfcv[i0] = bfc[i0]; }
    }
    __syncthreads(); // B3

    // ---- decoder temporal attention ----
    for (int i = tid; i < NT * NH; i += 256) {
        const int t = i / NH, k = i - t * NH;
        const float* wr = sW1c + k * ND;
        const float* hv = shs + t * NH;
        float a = sb1[k];
        for (int jj = 0; jj < ND; ++jj) a += wr[jj] * hv[jj];
        sdec[i] = sW2v[k] * tanh_(a);
    }
    __syncthreads();

    if (tid < NT) {
        float a = 0.0f;
        for (int k = 0; k < NH; ++k) a += sdec[tid * NH + k];
        sat[tid] = a; // b2 cancels in softmax
    }
    __syncthreads();
    if (tid == 0) {
        float m = -1e30f;
        for (int t = 0; t < NT; ++t) m = fmaxf(m, sat[t]);
        float e[NT], s = 0.0f;
        for (int t = 0; t < NT; ++t) { e[t] = __expf(sat[t] - m); s += e[t]; }
        const float inv = rcp_(s);
        for (int t = 0; t < NT; ++t) sat[t] = e[t] * inv;
    }
    __syncthreads();

    if (tid < NH) {
        float a = 0.0f;
        for (int t = 0; t < NT; ++t) a += sat[t] * shs[t * NH + tid];
        sctx[tid] = a;
    }
    __syncthreads();

    // ---- decoder LSTM (h=c=0): gate g from registers held since t=0 ----
    if (wave > 0 && g < NG) {
        float a = bd;
#pragma unroll
        for (int d = 0; d < 45; ++d) a += wd[d] * sctx[d];
        sg[g] = a;
    }
    __syncthreads();
    if (tid < NH) {
        const float ig = sigf(sg[tid]);
        const float gg = tanh_(sg[2 * NH + tid]);
        const float og = sigf(sg[3 * NH + tid]);
        sh1v[tid] = og * tanh_(ig * gg); // c0 = 0
    }
    __syncthreads();

    // ---- final fc: y = [h1, ctx] @ Wfc.T + bfc ----
    if (tid < 45) {
        const float* wr = sWfc + tid * (2 * NH);
        float a = sbfcv[tid];
        for (int jj = 0; jj < NH; ++jj) a += wr[jj] * sh1v[jj];
        for (int jj = 0; jj < NH; ++jj) a += wr[NH + jj] * sctx[jj];
        out[tid] = a;
    }
}

extern "C" void kernel_launch(void* const* d_in, const int* in_sizes, int n_in,
                              void* d_out, int out_size, void* d_ws, size_t ws_size,
                              hipStream_t stream) {
    const float* X     = (const float*)d_in[0];
    const float* Wa    = (const float*)d_in[1];
    // d_in[2] = ba — dead
    const float* Wih_e = (const float*)d_in[3];
    const float* Whh_e = (const float*)d_in[4];
    const float* bih_e = (const float*)d_in[5];
    const float* bhh_e = (const float*)d_in[6];
    const float* W1    = (const float*)d_in[7];
    const float* b1    = (const float*)d_in[8];
    const float* W2    = (const float*)d_in[9];
    // d_in[10] = b2 — dead
    const float* Wih_d = (const float*)d_in[11];
    // d_in[12] = Whh_d — dead
    const float* bih_d = (const float*)d_in[13];
    const float* bhh_d = (const float*)d_in[14];
    const float* Wfc   = (const float*)d_in[15];
    const float* bfc   = (const float*)d_in[16];
    float* out = (float*)d_out;

    darnn_kernel<<<dim3(1), dim3(256), 0, stream>>>(
        X, Wa, Wih_e, Whh_e, bih_e, bhh_e, W1, b1, W2,
        Wih_d, bih_d, bhh_d, Wfc, bfc, out);
}